// Round 7
// baseline (388.715 us; speedup 1.0000x reference)
//
#include <hip/hip_runtime.h>
#include <hip/hip_bf16.h>

#define NN 6144
#define INPUT 1024
#define HID 256

using frag  = __attribute__((ext_vector_type(8))) short;   // 8 bf16
using f32x4 = __attribute__((ext_vector_type(4))) float;

typedef __attribute__((address_space(3))) unsigned int lds_u32;
typedef const __attribute__((address_space(1))) unsigned int glb_u32;

// async global->LDS DMA: lane i of the wave moves 16B to (uniform base)+i*16
static __device__ __forceinline__ void dma16(const void* g, void* l) {
    __builtin_amdgcn_global_load_lds((glb_u32*)g, (lds_u32*)l, 16, 0, 0);
}

static __device__ __forceinline__ unsigned short bf16u(float x) {
    unsigned u = __float_as_uint(x);
    u += 0x7fff + ((u >> 16) & 1);     // RNE
    return (unsigned short)(u >> 16);
}

// ---------------- convert X -> bf16 row-major ----------------
__global__ __launch_bounds__(256) void k_convert_x(const float* __restrict__ X,
                                                   unsigned short* __restrict__ Xb) {
    int t = blockIdx.x * 256 + threadIdx.x;
    float4 v = reinterpret_cast<const float4*>(X)[t];
    ushort4 o;
    o.x = bf16u(v.x); o.y = bf16u(v.y); o.z = bf16u(v.z); o.w = bf16u(v.w);
    reinterpret_cast<ushort4*>(Xb)[t] = o;
}

// ---------------- convert W -> Wt bf16 transposed [HID][INPUT] ----------------
__global__ __launch_bounds__(256) void k_convert_w(const float* __restrict__ W,
                                                   unsigned short* __restrict__ Wt) {
    int t = blockIdx.x * 256 + threadIdx.x;          // t = n*1024 + k
    int n = t >> 10, k = t & 1023;
    Wt[t] = bf16u(W[k * HID + n]);
}

// ---------------- k_mm: split-K MFMA GEMM, Out[z] (+)= A-slice @ B-slice^T ----------------
// C[i][n] = sum_k A[i][aoff+z*Kblk+k] * B[n][boff+z*Kblk+k].
// Block 128 thr = 2 waves; tile M=32 (wave w: rows i0+w*16..+15) x N=64 (4 frags);
// BK=64 (2 k-sub-blocks of 32) -> LDS 12KB; grid (M/32, N/64, S).
// DMA-staged A and B in fragment order; 2 barriers per chunk.
__global__ __launch_bounds__(128) void k_mm(const unsigned short* __restrict__ A, int lda,
                                            const unsigned short* __restrict__ B, int ldb,
                                            int aoff, int boff, int Kblk,
                                            float* __restrict__ Out, int accumulate) {
    __shared__ unsigned short As[2][2][512];   // [wave][kk][lane*8]  4KB
    __shared__ unsigned short Bs[2][4][512];   // [kk][nt][lane*8]    8KB
    int t = threadIdx.x, w = t >> 6, l = t & 63, lm = l & 15, q = l >> 4;
    int i0 = blockIdx.x * 32, n0 = blockIdx.y * 64, z = blockIdx.z;

    const unsigned short* ga  = A + (size_t)(i0 + w * 16 + lm) * lda + aoff + (size_t)z * Kblk + q * 8;
    const unsigned short* gb0 = B + (size_t)(n0 + (2 * w) * 16 + lm) * ldb + boff + (size_t)z * Kblk + q * 8;
    const unsigned short* gb1 = gb0 + (size_t)16 * ldb;

    f32x4 acc[4] = {};
    int nch = Kblk >> 6;

    for (int c = 0; c < nch; c++) {
        int kc = c * 64;
        if (c) __syncthreads();                 // previous consume done before overwrite
        dma16(ga + kc,       &As[w][0][0]);
        dma16(ga + kc + 32,  &As[w][1][0]);
        dma16(gb0 + kc,      &Bs[0][2 * w][0]);
        dma16(gb0 + kc + 32, &Bs[1][2 * w][0]);
        dma16(gb1 + kc,      &Bs[0][2 * w + 1][0]);
        dma16(gb1 + kc + 32, &Bs[1][2 * w + 1][0]);
        __syncthreads();                        // drains DMA + publishes LDS
#pragma unroll
        for (int kk = 0; kk < 2; kk++) {
            frag a = *reinterpret_cast<const frag*>(&As[w][kk][l * 8]);
#pragma unroll
            for (int nt = 0; nt < 4; nt++) {
                frag b = *reinterpret_cast<const frag*>(&Bs[kk][nt][l * 8]);
                acc[nt] = __builtin_amdgcn_mfma_f32_16x16x32_bf16(a, b, acc[nt], 0, 0, 0);
            }
        }
    }

    // epilogue: C/D layout col=lm, row=q*4+r; partial buffer z
    float* Oz = Out + (size_t)z * NN * HID;
    int ib = i0 + w * 16 + q * 4;
    if (accumulate) {
#pragma unroll
        for (int nt = 0; nt < 4; nt++)
#pragma unroll
            for (int r = 0; r < 4; r++) {
                size_t off = (size_t)(ib + r) * HID + n0 + nt * 16 + lm;
                Oz[off] += acc[nt][r];
            }
    } else {
#pragma unroll
        for (int nt = 0; nt < 4; nt++)
#pragma unroll
            for (int r = 0; r < 4; r++) {
                size_t off = (size_t)(ib + r) * HID + n0 + nt * 16 + lm;
                Oz[off] = acc[nt][r];
            }
    }
}

// ---------------- k_hsum: h = sum of 4 partials -> hT bf16 + s1/s2 ----------------
// grid NN/4; block 256 = 4 waves; wave w owns row i = blk*4+w (lane l: n = l*4..l*4+3).
__global__ __launch_bounds__(256) void k_hsum(const float* __restrict__ Hp,
                                              const float* __restrict__ a_edge,
                                              unsigned short* __restrict__ hT,
                                              float* __restrict__ s1,
                                              float* __restrict__ s2) {
    __shared__ unsigned short T[4][256];
    int t = threadIdx.x, w = t >> 6, l = t & 63;
    int i0 = blockIdx.x * 4, i = i0 + w;
    size_t S = (size_t)NN * HID;
    size_t base = (size_t)i * HID + l * 4;

    float4 h0 = *reinterpret_cast<const float4*>(Hp + base);
    float4 h1 = *reinterpret_cast<const float4*>(Hp + base + S);
    float4 h2 = *reinterpret_cast<const float4*>(Hp + base + 2 * S);
    float4 h3 = *reinterpret_cast<const float4*>(Hp + base + 3 * S);
    float4 hv;
    hv.x = (h0.x + h1.x) + (h2.x + h3.x);
    hv.y = (h0.y + h1.y) + (h2.y + h3.y);
    hv.z = (h0.z + h1.z) + (h2.z + h3.z);
    hv.w = (h0.w + h1.w) + (h2.w + h3.w);

    // s1/s2 row dots (full 64-lane shuffle reduce)
    float4 a1 = reinterpret_cast<const float4*>(a_edge)[l];
    float4 a2 = reinterpret_cast<const float4*>(a_edge + HID)[l];
    float v1 = hv.x * a1.x + hv.y * a1.y + hv.z * a1.z + hv.w * a1.w;
    float v2 = hv.x * a2.x + hv.y * a2.y + hv.z * a2.z + hv.w * a2.w;
#pragma unroll
    for (int m = 1; m <= 32; m <<= 1) {
        v1 += __shfl_xor(v1, m);
        v2 += __shfl_xor(v2, m);
    }
    if (l == 0) { s1[i] = v1; s2[i] = v2; }

    // transpose to hT[n][i] via LDS
    ushort4 hb;
    hb.x = bf16u(hv.x); hb.y = bf16u(hv.y); hb.z = bf16u(hv.z); hb.w = bf16u(hv.w);
    *reinterpret_cast<ushort4*>(&T[w][l * 4]) = hb;
    __syncthreads();
    int n = t;   // 0..255
    ushort4 o;
    o.x = T[0][n]; o.y = T[1][n]; o.z = T[2][n]; o.w = T[3][n];
    *reinterpret_cast<ushort4*>(hT + (size_t)n * NN + i0) = o;
}

// ---------------- k_build: P strip = exp(leaky(s1+s2)) masked, + denom row-sums ----------------
__global__ __launch_bounds__(256) void k_build(const int* __restrict__ adj,
                                               const float* __restrict__ s1,
                                               const float* __restrict__ s2,
                                               unsigned short* __restrict__ P,
                                               float* __restrict__ denom,
                                               int j0, int Kstrip) {
    __shared__ float red[4];
    int i = blockIdx.x, t = threadIdx.x;
    float s1v = s1[i];
    const int* ar = adj + (size_t)i * NN + j0;
    const float* sp = s2 + j0;
    unsigned short* pr = P + (size_t)i * Kstrip;
    float dsum = 0.f;

    for (int seg = 0; seg < Kstrip; seg += 1024) {
        int c = seg + t * 4;
        int4   av = *reinterpret_cast<const int4*>(ar + c);
        float4 sv = *reinterpret_cast<const float4*>(sp + c);
        float sc, e, p0, p1, p2, p3;
        sc = s1v + sv.x; e = __expf(fmaxf(sc, 0.2f * sc)); p0 = av.x ? e : 0.f;
        sc = s1v + sv.y; e = __expf(fmaxf(sc, 0.2f * sc)); p1 = av.y ? e : 0.f;
        sc = s1v + sv.z; e = __expf(fmaxf(sc, 0.2f * sc)); p2 = av.z ? e : 0.f;
        sc = s1v + sv.w; e = __expf(fmaxf(sc, 0.2f * sc)); p3 = av.w ? e : 0.f;
        dsum += (p0 + p1) + (p2 + p3);
        ushort4 o;
        o.x = bf16u(p0); o.y = bf16u(p1); o.z = bf16u(p2); o.w = bf16u(p3);
        *reinterpret_cast<ushort4*>(pr + c) = o;
    }

    dsum += __shfl_xor(dsum, 1);  dsum += __shfl_xor(dsum, 2);
    dsum += __shfl_xor(dsum, 4);  dsum += __shfl_xor(dsum, 8);
    dsum += __shfl_xor(dsum, 16); dsum += __shfl_xor(dsum, 32);
    if ((t & 63) == 0) red[t >> 6] = dsum;
    __syncthreads();
    if (t == 0) denom[i] += red[0] + red[1] + red[2] + red[3];   // strip-serial
}

// ---------------- normalize: out = (sum_z Up[z]) / denom ----------------
__global__ __launch_bounds__(256) void k_norm(const float* __restrict__ Up,
                                              const float* __restrict__ denom,
                                              float* __restrict__ out) {
    int i = blockIdx.x, t = threadIdx.x;
    size_t S = (size_t)NN * HID;
    size_t base = (size_t)i * HID + t;
    float u = (Up[base] + Up[base + S]) + (Up[base + 2 * S] + Up[base + 3 * S]);
    float d = denom[i];
    out[base] = (d != 0.f) ? u / d : 0.f;
}

extern "C" void kernel_launch(void* const* d_in, const int* in_sizes, int n_in,
                              void* d_out, int out_size, void* d_ws, size_t ws_size,
                              hipStream_t stream) {
    const float* X      = (const float*)d_in[0];   // 6144x1024
    const float* W      = (const float*)d_in[1];   // 1024x256
    const float* a_edge = (const float*)d_in[2];   // 512
    const int*   adj    = (const int*)d_in[3];     // 6144x6144
    float* out = (float*)d_out;

    // workspace: Up[4] partials (Up[0] = final U accumulator space) + small vecs + bf16 bufs + P
    float* Up    = (float*)d_ws;                         // 4*NN*HID f32 (25.2 MB)
    float* denom = Up + (size_t)4 * NN * HID;            // NN
    float* s1    = denom + NN;                           // NN
    float* s2    = s1 + NN;                              // NN
    unsigned short* hT = (unsigned short*)(s2 + NN);     // HID*NN bf16 (3.1 MB)
    unsigned short* Xb = hT + (size_t)HID * NN;          // NN*INPUT bf16 (12.6 MB)
    unsigned short* Wt = Xb + (size_t)NN * INPUT;        // HID*INPUT bf16 (0.5 MB)
    unsigned short* P  = Wt + (size_t)HID * INPUT;       // NN*Kstrip bf16

    size_t fixedB = ((size_t)4 * NN * HID + 3 * NN) * sizeof(float)
                  + ((size_t)HID * NN + (size_t)NN * INPUT + (size_t)HID * INPUT) * 2;
    int ns;                                    // strips; Kstrip mult of 1024 and 256
    if      (fixedB + (size_t)NN * NN * 2       <= ws_size) ns = 1;
    else if (fixedB + (size_t)NN * (NN / 2) * 2 <= ws_size) ns = 2;
    else if (fixedB + (size_t)NN * (NN / 3) * 2 <= ws_size) ns = 3;
    else                                                    ns = 6;
    int Kstrip = NN / ns;

    hipMemsetAsync(denom, 0, NN * sizeof(float), stream);
    k_convert_x<<<NN * INPUT / 1024, 256, 0, stream>>>(X, Xb);
    k_convert_w<<<INPUT * HID / 256, 256, 0, stream>>>(W, Wt);
    // gemm1: h partials into Up[0..3]; K=1024, 4 splits of 256
    k_mm<<<dim3(NN / 32, HID / 64, 4), 128, 0, stream>>>(Xb, INPUT, Wt, INPUT,
                                                         0, 0, INPUT / 4, Up, 0);
    k_hsum<<<NN / 4, 256, 0, stream>>>(Up, a_edge, hT, s1, s2);
    for (int s = 0; s < ns; s++) {
        int j0 = s * Kstrip;
        k_build<<<NN, 256, 0, stream>>>(adj, s1, s2, P, denom, j0, Kstrip);
        // gemm2: Up[z] (strip0: store, else accumulate); A=P (lda=Kstrip), B=hT (ldb=NN, boff=j0)
        k_mm<<<dim3(NN / 32, HID / 64, 4), 128, 0, stream>>>(P, Kstrip, hT, NN,
                                                             0, j0, Kstrip / 4, Up, s ? 1 : 0);
    }
    k_norm<<<NN, 256, 0, stream>>>(Up, denom, out);
}

// Round 8
// 372.674 us; speedup vs baseline: 1.0430x; 1.0430x over previous
//
#include <hip/hip_runtime.h>
#include <hip/hip_bf16.h>

#define NN 6144
#define INPUT 1024
#define HID 256

using frag  = __attribute__((ext_vector_type(8))) short;   // 8 bf16
using f32x4 = __attribute__((ext_vector_type(4))) float;

typedef __attribute__((address_space(3))) unsigned int lds_u32;
typedef const __attribute__((address_space(1))) unsigned int glb_u32;

// async global->LDS DMA: lane i of the wave moves 16B to (uniform base)+i*16
static __device__ __forceinline__ void dma16(const void* g, void* l) {
    __builtin_amdgcn_global_load_lds((glb_u32*)g, (lds_u32*)l, 16, 0, 0);
}

static __device__ __forceinline__ unsigned short bf16u(float x) {
    unsigned u = __float_as_uint(x);
    u += 0x7fff + ((u >> 16) & 1);     // RNE
    return (unsigned short)(u >> 16);
}

// Fragment-linear layout (both A-side rows and B-side rows use the same formula):
//   pk[(rb*BPR + kb)*512 + l*8 + e]  holds  M[rb*16 + (l&15)][kb*32 + (l>>4)*8 + e]
// where rb = row/16, kb = col/32, BPR = (row-block's K extent)/32.
// A wave reading one (rb,kb) block touches exactly 1KB contiguous.

// ---------------- convert X (f32 row-major) -> Xpk ----------------
__global__ __launch_bounds__(256) void k_convert_x(const float* __restrict__ X,
                                                   unsigned short* __restrict__ Xpk) {
    int t = blockIdx.x * 256 + threadIdx.x;      // NN*INPUT/4 threads
    int i = t >> 8, c = (t & 255) * 4;
    float4 v = *reinterpret_cast<const float4*>(X + (size_t)i * INPUT + c);
    ushort4 o;
    o.x = bf16u(v.x); o.y = bf16u(v.y); o.z = bf16u(v.z); o.w = bf16u(v.w);
    size_t addr = ((size_t)(i >> 4) * (INPUT / 32) + (c >> 5)) * 512
                + ((((c >> 3) & 3) << 4) | (i & 15)) * 8 + (c & 7);
    *reinterpret_cast<ushort4*>(Xpk + addr) = o;
}

// ---------------- convert W [INPUT][HID] -> Wpk (B-side: rows=n, k=input dim) ----------------
__global__ __launch_bounds__(256) void k_convert_w(const float* __restrict__ W,
                                                   unsigned short* __restrict__ Wpk) {
    int t = blockIdx.x * 256 + threadIdx.x;      // INPUT*HID/4 threads
    int k = t >> 6, n4 = (t & 63) * 4;
    float4 v = *reinterpret_cast<const float4*>(W + (size_t)k * HID + n4);
    float vv[4] = {v.x, v.y, v.z, v.w};
#pragma unroll
    for (int j = 0; j < 4; j++) {
        int n = n4 + j;
        size_t addr = ((size_t)(n >> 4) * (INPUT / 32) + (k >> 5)) * 512
                    + ((((k >> 3) & 3) << 4) | (n & 15)) * 8 + (k & 7);
        Wpk[addr] = bf16u(vv[j]);
    }
}

// ---------------- k_mm: split-K MFMA GEMM on fragment-linear operands ----------------
// Out[z] (+)= A @ B^T restricted to k in [z*Kblk, (z+1)*Kblk).
// Block 128 thr = 2 waves; tile M=32 x N=128; BK=64; LDS 20KB; grid (NN/32, HID/128, 4).
// All staging DMAs are contiguous 1KB per wave-instruction.
__global__ __launch_bounds__(128, 4) void k_mm(const unsigned short* __restrict__ Apk, int aBPR,
                                               const unsigned short* __restrict__ Bpk, int bBPR,
                                               int a_kb0, int b_kb0, int Kblk,
                                               float* __restrict__ Out, int accumulate) {
    __shared__ unsigned short As[4][512];     // slot mi*2+kk   (4 KB)
    __shared__ unsigned short Bs[16][512];    // slot nbG*2+kk  (16 KB)
    int t = threadIdx.x, w = t >> 6, l = t & 63, lm = l & 15, q = l >> 4;
    int i0 = blockIdx.x * 32, n0 = blockIdx.y * 128, z = blockIdx.z;

    const unsigned short* aB = Apk + ((size_t)(i0 >> 4) * aBPR + a_kb0 + ((z * Kblk) >> 5)) * 512 + l * 8;
    const unsigned short* bB = Bpk + ((size_t)(n0 >> 4) * bBPR + b_kb0 + ((z * Kblk) >> 5)) * 512 + l * 8;

    f32x4 acc[2][4] = {};
    int nch = Kblk >> 6;

    for (int c = 0; c < nch; c++) {
        if (c) __syncthreads();                 // previous consume done before overwrite
        // A: wave w stages mi=w, kk=0,1 (contiguous 1KB each)
        dma16(aB + (size_t)w * aBPR * 512,        &As[w * 2 + 0][0]);
        dma16(aB + ((size_t)w * aBPR + 1) * 512,  &As[w * 2 + 1][0]);
        // B: wave w stages its n-half's 4 row-blocks, kk=0,1
#pragma unroll
        for (int nb = 0; nb < 4; nb++) {
            int nbG = w * 4 + nb;
            dma16(bB + (size_t)nbG * bBPR * 512,       &Bs[nbG * 2 + 0][0]);
            dma16(bB + ((size_t)nbG * bBPR + 1) * 512, &Bs[nbG * 2 + 1][0]);
        }
        __syncthreads();                        // drains DMA + publishes LDS
#pragma unroll
        for (int kk = 0; kk < 2; kk++) {
            frag a0 = *reinterpret_cast<const frag*>(&As[kk][l * 8]);
            frag a1 = *reinterpret_cast<const frag*>(&As[2 + kk][l * 8]);
#pragma unroll
            for (int nb = 0; nb < 4; nb++) {
                frag b = *reinterpret_cast<const frag*>(&Bs[(w * 4 + nb) * 2 + kk][l * 8]);
                acc[0][nb] = __builtin_amdgcn_mfma_f32_16x16x32_bf16(a0, b, acc[0][nb], 0, 0, 0);
                acc[1][nb] = __builtin_amdgcn_mfma_f32_16x16x32_bf16(a1, b, acc[1][nb], 0, 0, 0);
            }
        }
        aB += 1024;    // advance kb by 2 blocks
        bB += 1024;
    }

    // epilogue: C/D layout col=lm, row=q*4+r; z-partial buffer
    float* Oz = Out + (size_t)z * NN * HID;
#pragma unroll
    for (int mi = 0; mi < 2; mi++)
#pragma unroll
        for (int nb = 0; nb < 4; nb++)
#pragma unroll
            for (int r = 0; r < 4; r++) {
                size_t off = (size_t)(i0 + mi * 16 + q * 4 + r) * HID + n0 + w * 64 + nb * 16 + lm;
                if (accumulate) Oz[off] += acc[mi][nb][r];
                else            Oz[off]  = acc[mi][nb][r];
            }
}

// ---------------- k_hsum: h = sum of 4 partials -> hpk (B-side frag layout) + s1/s2 ----------------
// grid NN/4; block 256 = 4 waves; wave w owns row i = blk*4+w; lane l: n = 4l..4l+3.
__global__ __launch_bounds__(256) void k_hsum(const float* __restrict__ Hp,
                                              const float* __restrict__ a_edge,
                                              unsigned short* __restrict__ hpk,
                                              float* __restrict__ s1,
                                              float* __restrict__ s2) {
    int t = threadIdx.x, w = t >> 6, l = t & 63;
    int i = blockIdx.x * 4 + w;
    size_t S = (size_t)NN * HID;
    size_t base = (size_t)i * HID + l * 4;

    float4 h0 = *reinterpret_cast<const float4*>(Hp + base);
    float4 h1 = *reinterpret_cast<const float4*>(Hp + base + S);
    float4 h2 = *reinterpret_cast<const float4*>(Hp + base + 2 * S);
    float4 h3 = *reinterpret_cast<const float4*>(Hp + base + 3 * S);
    float hv[4];
    hv[0] = (h0.x + h1.x) + (h2.x + h3.x);
    hv[1] = (h0.y + h1.y) + (h2.y + h3.y);
    hv[2] = (h0.z + h1.z) + (h2.z + h3.z);
    hv[3] = (h0.w + h1.w) + (h2.w + h3.w);

    // s1/s2 row dots
    float4 a1 = reinterpret_cast<const float4*>(a_edge)[l];
    float4 a2 = reinterpret_cast<const float4*>(a_edge + HID)[l];
    float v1 = hv[0] * a1.x + hv[1] * a1.y + hv[2] * a1.z + hv[3] * a1.w;
    float v2 = hv[0] * a2.x + hv[1] * a2.y + hv[2] * a2.z + hv[3] * a2.w;
#pragma unroll
    for (int m = 1; m <= 32; m <<= 1) {
        v1 += __shfl_xor(v1, m);
        v2 += __shfl_xor(v2, m);
    }
    if (l == 0) { s1[i] = v1; s2[i] = v2; }

    // hpk write: rows = n (HID of them), k-dim = i over NN
    size_t ibpart = ((size_t)(i >> 5)) * 512 + ((((i >> 3) & 3) << 4)) * 8 + (i & 7);
#pragma unroll
    for (int j = 0; j < 4; j++) {
        int n = 4 * l + j;
        size_t addr = (size_t)(n >> 4) * (NN / 32) * 512 + ibpart + (size_t)(n & 15) * 8;
        hpk[addr] = bf16u(hv[j]);
    }
}

// ---------------- k_build: Ppk strip (A-side frag layout) + denom row-sums ----------------
__global__ __launch_bounds__(256) void k_build(const int* __restrict__ adj,
                                               const float* __restrict__ s1,
                                               const float* __restrict__ s2,
                                               unsigned short* __restrict__ Ppk,
                                               float* __restrict__ denom,
                                               int j0, int Kstrip) {
    __shared__ float red[4];
    int i = blockIdx.x, t = threadIdx.x;
    float s1v = s1[i];
    const int* ar = adj + (size_t)i * NN + j0;
    const float* sp = s2 + j0;
    size_t rowbase = (size_t)(i >> 4) * (Kstrip >> 5) * 512 + (size_t)(i & 15) * 8;
    float dsum = 0.f;

    for (int seg = 0; seg < Kstrip; seg += 1024) {
        int c = seg + t * 4;
        int4   av = *reinterpret_cast<const int4*>(ar + c);
        float4 sv = *reinterpret_cast<const float4*>(sp + c);
        float sc, e, p0, p1, p2, p3;
        sc = s1v + sv.x; e = __expf(fmaxf(sc, 0.2f * sc)); p0 = av.x ? e : 0.f;
        sc = s1v + sv.y; e = __expf(fmaxf(sc, 0.2f * sc)); p1 = av.y ? e : 0.f;
        sc = s1v + sv.z; e = __expf(fmaxf(sc, 0.2f * sc)); p2 = av.z ? e : 0.f;
        sc = s1v + sv.w; e = __expf(fmaxf(sc, 0.2f * sc)); p3 = av.w ? e : 0.f;
        dsum += (p0 + p1) + (p2 + p3);
        ushort4 o;
        o.x = bf16u(p0); o.y = bf16u(p1); o.z = bf16u(p2); o.w = bf16u(p3);
        size_t addr = rowbase + (size_t)(c >> 5) * 512
                    + (size_t)(((c >> 3) & 3) << 7) + (c & 7);
        *reinterpret_cast<ushort4*>(Ppk + addr) = o;
    }

    dsum += __shfl_xor(dsum, 1);  dsum += __shfl_xor(dsum, 2);
    dsum += __shfl_xor(dsum, 4);  dsum += __shfl_xor(dsum, 8);
    dsum += __shfl_xor(dsum, 16); dsum += __shfl_xor(dsum, 32);
    if ((t & 63) == 0) red[t >> 6] = dsum;
    __syncthreads();
    if (t == 0) denom[i] += red[0] + red[1] + red[2] + red[3];   // strip-serial
}

// ---------------- normalize: out = (sum_z Up[z]) / denom ----------------
__global__ __launch_bounds__(256) void k_norm(const float* __restrict__ Up,
                                              const float* __restrict__ denom,
                                              float* __restrict__ out) {
    int i = blockIdx.x, t = threadIdx.x;
    size_t S = (size_t)NN * HID;
    size_t base = (size_t)i * HID + t;
    float u = (Up[base] + Up[base + S]) + (Up[base + 2 * S] + Up[base + 3 * S]);
    float d = denom[i];
    out[base] = (d != 0.f) ? u / d : 0.f;
}

extern "C" void kernel_launch(void* const* d_in, const int* in_sizes, int n_in,
                              void* d_out, int out_size, void* d_ws, size_t ws_size,
                              hipStream_t stream) {
    const float* X      = (const float*)d_in[0];   // 6144x1024
    const float* W      = (const float*)d_in[1];   // 1024x256
    const float* a_edge = (const float*)d_in[2];   // 512
    const int*   adj    = (const int*)d_in[3];     // 6144x6144
    float* out = (float*)d_out;

    float* Up    = (float*)d_ws;                         // 4*NN*HID f32 (25.2 MB)
    float* denom = Up + (size_t)4 * NN * HID;            // NN
    float* s1    = denom + NN;                           // NN
    float* s2    = s1 + NN;                              // NN
    unsigned short* hpk = (unsigned short*)(s2 + NN);    // HID*NN bf16 (3.1 MB)
    unsigned short* Xpk = hpk + (size_t)HID * NN;        // NN*INPUT bf16 (12.6 MB)
    unsigned short* Wpk = Xpk + (size_t)NN * INPUT;      // HID*INPUT bf16 (0.5 MB)
    unsigned short* Ppk = Wpk + (size_t)HID * INPUT;     // NN*Kstrip bf16

    size_t fixedB = ((size_t)4 * NN * HID + 3 * NN) * sizeof(float)
                  + ((size_t)HID * NN + (size_t)NN * INPUT + (size_t)HID * INPUT) * 2;
    int ns;                                    // strips; Kstrip mult of 1024 and 256
    if      (fixedB + (size_t)NN * NN * 2       <= ws_size) ns = 1;
    else if (fixedB + (size_t)NN * (NN / 2) * 2 <= ws_size) ns = 2;
    else if (fixedB + (size_t)NN * (NN / 3) * 2 <= ws_size) ns = 3;
    else                                                    ns = 6;
    int Kstrip = NN / ns;

    hipMemsetAsync(denom, 0, NN * sizeof(float), stream);
    k_convert_x<<<NN * INPUT / 1024, 256, 0, stream>>>(X, Xpk);
    k_convert_w<<<INPUT * HID / 1024, 256, 0, stream>>>(W, Wpk);
    // gemm1: h z-partials into Up; A=Xpk (aBPR=32), B=Wpk (bBPR=32), Kblk=256
    k_mm<<<dim3(NN / 32, HID / 128, 4), 128, 0, stream>>>(Xpk, INPUT / 32, Wpk, INPUT / 32,
                                                          0, 0, INPUT / 4, Up, 0);
    k_hsum<<<NN / 4, 256, 0, stream>>>(Up, a_edge, hpk, s1, s2);
    for (int s = 0; s < ns; s++) {
        int j0 = s * Kstrip;
        k_build<<<NN, 256, 0, stream>>>(adj, s1, s2, Ppk, denom, j0, Kstrip);
        // gemm2: A=Ppk (aBPR=Kstrip/32, strip-relative), B=hpk (bBPR=NN/32, offset j0/32)
        k_mm<<<dim3(NN / 32, HID / 128, 4), 128, 0, stream>>>(Ppk, Kstrip / 32, hpk, NN / 32,
                                                              0, j0 / 32, Kstrip / 4, Up, s ? 1 : 0);
    }
    k_norm<<<NN, 256, 0, stream>>>(Up, denom, out);
}